// Round 2
// baseline (515.355 us; speedup 1.0000x reference)
//
#include <hip/hip_runtime.h>
#include <hip/hip_bf16.h>
#include <stdint.h>
#include <stddef.h>

typedef unsigned short ushort_t;
typedef unsigned int uint_t;

typedef __attribute__((ext_vector_type(8))) short short8;
typedef __attribute__((ext_vector_type(4))) float floatx4;
typedef __attribute__((ext_vector_type(16))) float floatx16;
typedef __attribute__((ext_vector_type(4))) uint_t uintx4;

#define N_ROWS 32768
#define K_ENT  8192
#define CDIM   256
#define OUT_ELEMS 8388608
#define LOSS_OFF  8388608
#define IDX_OFF   8388609
// Per-(row, k-quarter) survivor list capacity. Measured (r8): single-pass
// running-max appends are ~20 per quarter; CAP_Q=44 puts overflow at ~1e-6.
#define CAP_Q  44
// Margin: covers bf16 rounding of z,c + reference fp32 quantization ulp(256).
// Refine re-filters stored candidates against the FINAL row max (max of stored
// vals), reproducing the two-phase survivor set. MFMA-shape change only
// perturbs fp32 accumulation order (~1e-10), negligible vs MARGIN.
#define MARGIN    2.0e-4f

// RNE float -> bf16 bits
__device__ __forceinline__ ushort_t f2bf(float f) {
    uint_t x = __float_as_uint(f);
    uint_t r = (x + 0x7fffu + ((x >> 16) & 1u)) >> 16;
    return (ushort_t)r;
}

// Swizzled layout for mfma_32x32x16 fragments: element (row, c) lives at
//   (row>>5)*8192 + (c>>4)*512 + ((c>>3)&1)*256 + (row&31)*8 + (c&7)   [ushort idx]
// -> fragment load for k-step s (lane l: row r0+(l&31), dims s*16+(l>>5)*8, 16 B)
//    is one contiguous 1 KiB per (rowgroup, s); a 32-ent tile is 16 KB contiguous
//    and LINEAR -> global_load_lds(16B) staging works with a linear LDS dest.

__device__ __forceinline__ void gload_lds16(const ushort_t* g, ushort_t* s) {
    __builtin_amdgcn_global_load_lds(
        (__attribute__((address_space(1))) void*)(g),
        (__attribute__((address_space(3))) void*)(s), 16, 0, 0);
}

// Fused prep: blocks [0,2048) transpose z -> swizzled bf16 (+ fp32 ztf copy);
// blocks [2048,3072) pack codebook -> swizzled bf16 and init cnt/cnt2/acc.
__global__ __launch_bounds__(256) void k_prep(const float* __restrict__ zin,
                                              const float* __restrict__ cb,
                                              ushort_t* __restrict__ zsw,
                                              ushort_t* __restrict__ cbsw,
                                              float* __restrict__ ztf,
                                              int* __restrict__ cnt,
                                              int* __restrict__ cnt2,
                                              double* __restrict__ acc) {
    int bid = blockIdx.x;
    if (bid >= 2048) {
        int t = (bid - 2048) * 256 + threadIdx.x;   // 262,144 items
        if (t < N_ROWS * 4) cnt[t] = 0;
        if (t == 0) { *acc = 0.0; *cnt2 = 0; }
        int ent = t >> 5;
        int c0  = (t & 31) << 3;
        const float* p = cb + (size_t)ent * CDIM + c0;
        floatx4 f0 = *(const floatx4*)p;
        floatx4 f1 = *(const floatx4*)(p + 4);
        uintx4 pk;
        pk[0] = (uint_t)f2bf(f0[0]) | ((uint_t)f2bf(f0[1]) << 16);
        pk[1] = (uint_t)f2bf(f0[2]) | ((uint_t)f2bf(f0[3]) << 16);
        pk[2] = (uint_t)f2bf(f1[0]) | ((uint_t)f2bf(f1[1]) << 16);
        pk[3] = (uint_t)f2bf(f1[2]) | ((uint_t)f2bf(f1[3]) << 16);
        int idx = (ent >> 5) * 8192 + (c0 >> 4) * 512 + ((c0 >> 3) & 1) * 256 + (ent & 31) * 8;
        *(uintx4*)(cbsw + idx) = pk;
        return;
    }
    __shared__ float lds[64][65];
    int c0 = (bid & 3) << 6;
    int s0 = ((bid >> 2) & 63) << 6;
    int b  = bid >> 8;
    int tid = threadIdx.x;
    int j = tid & 63, ib = tid >> 6;
    const float* zb = zin + ((size_t)b << 20);
#pragma unroll
    for (int rr = 0; rr < 16; ++rr) {
        int i = rr * 4 + ib;                       // c-local
        lds[i][j] = zb[(size_t)(c0 + i) * 4096 + s0 + j];   // coalesced over j
    }
    __syncthreads();
#pragma unroll
    for (int it = 0; it < 2; ++it) {
        int item = it * 256 + tid;                 // 512 items: (s-local, c-chunk)
        int sl = item >> 3;
        int ch = item & 7;
        int row = (b << 12) + s0 + sl;             // n
        int cg  = c0 + ch * 8;
        uintx4 pk;
        floatx4 f0, f1;
#pragma unroll
        for (int q = 0; q < 4; ++q) {
            float a = lds[ch * 8 + 2 * q][sl];
            float bqv = lds[ch * 8 + 2 * q + 1][sl];
            pk[q] = (uint_t)f2bf(a) | ((uint_t)f2bf(bqv) << 16);
        }
#pragma unroll
        for (int q = 0; q < 4; ++q) {
            f0[q] = lds[ch * 8 + q][sl];
            f1[q] = lds[ch * 8 + 4 + q][sl];
        }
        int idx = (row >> 5) * 8192 + (cg >> 4) * 512 + ((cg >> 3) & 1) * 256 + (row & 31) * 8;
        *(uintx4*)(zsw + idx) = pk;
        if (ztf) {
            *(floatx4*)(ztf + (size_t)row * 256 + cg) = f0;
            *(floatx4*)(ztf + (size_t)row * 256 + cg + 4) = f1;
        }
    }
}

// Per-tile max-reduce + survivor append for one row-group accumulator.
// C/D layout (32x32x16): col(z-row) = lane&31, ent = (r&3) + 8*(r>>2) + 4*(l>>5).
__device__ __forceinline__ void screen_emit(const floatx16& acc, float& rmx,
                                            int2* slist, int* cntp, int ent0) {
    float t0 = fmaxf(fmaxf(acc[0], acc[1]), fmaxf(acc[2], acc[3]));
    float t1 = fmaxf(fmaxf(acc[4], acc[5]), fmaxf(acc[6], acc[7]));
    float t2 = fmaxf(fmaxf(acc[8], acc[9]), fmaxf(acc[10], acc[11]));
    float t3 = fmaxf(fmaxf(acc[12], acc[13]), fmaxf(acc[14], acc[15]));
    float mx = fmaxf(fmaxf(t0, t1), fmaxf(t2, t3));
    mx = fmaxf(mx, __shfl_xor(mx, 32));   // other lane-half holds other 16 ents
    float rm = fmaxf(rmx, mx);
    rmx = rm;
    float thr = rm - MARGIN;
#pragma unroll
    for (int r = 0; r < 16; ++r) {
        float v = acc[r];
        if (v >= thr) {
            int ent = ent0 + (r & 3) + 8 * (r >> 2);
            int s = atomicAdd(cntp, 1);
            if (s < CAP_Q) slist[s] = make_int2(ent, __float_as_int(v));
        }
    }
}

// SINGLE-PASS bf16 MFMA screen, 32x32x16, entries on the accumulator register
// axis, z-rows on the lane axis. ROUND 2: each wave owns TWO 32-row z groups
// (zfr0/zfr1 in regs, 128 VGPR) so each codebook ds_read_b128 feeds 2 MFMAs --
// per-CU DS pipe drops below the matrix pipe (1536 vs 2048 cyc/kt) and the
// kernel becomes MFMA-bound at its ~55 us floor. Block = 4 waves x 64 rows =
// 256 rows, one k-quarter; grid 512 = exactly 2 blocks/CU; 32 KB dbuf LDS.
// Append semantics unchanged: any value within MARGIN of the RUNNING row max
// is stored; refine re-filters against the final max (= max stored value;
// record-setter always self-appends), reproducing the two-phase survivor set.
__global__ __launch_bounds__(256, 2) void k_screen(const ushort_t* __restrict__ zsw,
                                                   const ushort_t* __restrict__ cbsw,
                                                   int2* __restrict__ surv,
                                                   int* __restrict__ cnt) {
    __shared__ ushort_t bt[2][8192];    // 2 x 16 KB B tiles (32 ents each, linear)
    int tid = threadIdx.x;              // 0..255
    int w = tid >> 6, l = tid & 63;
    int bid = blockIdx.x;
    int q  = bid & 3;                   // k-quarter
    int RB = (bid >> 2) * 256;          // row base; wave w owns rows [RB+w*64, +64)
    int tile0 = q * 64;                 // first 32-ent tile of this quarter

    // prologue: stage tile 0 into buf 0 (16 KB = 256 threads x 16 B x 4)
#pragma unroll
    for (int j = 0; j < 4; ++j)
        gload_lds16(cbsw + (size_t)tile0 * 8192 + j * 2048 + tid * 8,
                    &bt[0][j * 2048 + w * 512]);

    // z fragments for both row-groups (B operand), held in regs all kernel
    short8 zfr0[16], zfr1[16];
    {
        const ushort_t* pz = zsw + (size_t)((RB >> 5) + w * 2) * 8192 + l * 8;
#pragma unroll
        for (int s = 0; s < 16; ++s) {
            zfr0[s] = *(const short8*)(pz + s * 512);
            zfr1[s] = *(const short8*)(pz + 8192 + s * 512);
        }
    }
    __syncthreads();

    int n0 = RB + w * 64 + (l & 31);    // row-group 0 z-row for this lane
    int cidx0 = n0 * 4 + q;
    int cidx1 = (n0 + 32) * 4 + q;
    int2* sl0 = surv + (size_t)cidx0 * CAP_Q;
    int2* sl1 = surv + (size_t)cidx1 * CAP_Q;
    float rmx0 = -3.0e38f, rmx1 = -3.0e38f;
    int esub = (l >> 5) * 4;

    for (int kt = 0; kt < 64; ++kt) {
        // prefetch next tile into other buffer (last iter re-stages tile 0)
        int bsel = (kt + 1) & 1;
        const ushort_t* gs = cbsw + (size_t)(tile0 + ((kt + 1) & 63)) * 8192;
#pragma unroll
        for (int j = 0; j < 4; ++j)
            gload_lds16(gs + j * 2048 + tid * 8, &bt[bsel][j * 2048 + w * 512]);

        const ushort_t* bb = &bt[kt & 1][l * 8];
        floatx16 acc0, acc1;
#pragma unroll
        for (int i = 0; i < 16; ++i) { acc0[i] = 0.f; acc1[i] = 0.f; }
#pragma unroll
        for (int s = 0; s < 16; ++s) {
            short8 a = *(const short8*)(bb + s * 512);   // codebook frag (A: ents)
            acc0 = __builtin_amdgcn_mfma_f32_32x32x16_bf16(a, zfr0[s], acc0, 0, 0, 0);
            acc1 = __builtin_amdgcn_mfma_f32_32x32x16_bf16(a, zfr1[s], acc1, 0, 0, 0);
        }
        int ent0 = (tile0 + kt) * 32 + esub;
        screen_emit(acc0, rmx0, sl0, &cnt[cidx0], ent0);
        screen_emit(acc1, rmx1, sl1, &cnt[cidx1], ent0);
        __syncthreads();                // drains vmcnt: next tile ready, buf reusable
    }
}

// Exact fp32 refine: gather <=176 stored (ent, bf16-dot) candidates from the 4
// quarter lists, filter by val >= finalmax - MARGIN (finalmax = max stored val;
// the record-setter always self-appends), then fp32 dots for the ~1-3 passing
// candidates. Serial fmaf order unchanged, so idx semantics are unchanged.
// Overflow (~1e-6 probability) -> 4-chain fast full-scan fallback.
__global__ __launch_bounds__(256) void k_refine(const float* __restrict__ zin,
                                                const float* __restrict__ ztf,
                                                const float* __restrict__ cb,
                                                const int2* __restrict__ surv,
                                                const int* __restrict__ cnt,
                                                int* __restrict__ idxi,
                                                float* __restrict__ idxf) {
    __shared__ float zr[4][256];
    int w = threadIdx.x >> 6, l = threadIdx.x & 63;
    int n = blockIdx.x * 4 + w;
    if (ztf) {
        const float* zrow = ztf + (size_t)n * 256;
#pragma unroll
        for (int i = 0; i < 4; ++i)
            zr[w][l + 64 * i] = zrow[l + 64 * i];          // coalesced
    } else {
        int b = n >> 12, s = n & 4095;
        const float* zb = zin + ((size_t)b << 20) + s;
#pragma unroll
        for (int i = 0; i < 4; ++i)
            zr[w][l + 64 * i] = zb[(size_t)(l + 64 * i) << 12];
    }
    __syncthreads();
    const float* z = zr[w];
    float zn = 0.f;
    for (int c = 0; c < 256; ++c) zn = fmaf(z[c], z[c], zn);

    int c0 = cnt[n * 4 + 0], c1 = cnt[n * 4 + 1];
    int c2 = cnt[n * 4 + 2], c3 = cnt[n * 4 + 3];
    int m = c0 + c1 + c2 + c3;
    bool ok = (c0 <= CAP_Q) && (c1 <= CAP_Q) && (c2 <= CAP_Q) && (c3 <= CAP_Q) && (m >= 1);
    float bu = 3.0e38f;
    int bk = 0x7fffffff;
    if (ok) {
        int myk[3]; float myv[3]; int nc = 0;
        float vmax = -3.0e38f;
        for (int i = l; i < m; i += 64) {
            int qq, s;
            if (i < c0)            { qq = 0; s = i; }
            else if (i < c0 + c1)  { qq = 1; s = i - c0; }
            else if (i < c0 + c1 + c2) { qq = 2; s = i - c0 - c1; }
            else                   { qq = 3; s = i - c0 - c1 - c2; }
            int2 kv = surv[(n * 4 + qq) * CAP_Q + s];
            myk[nc] = kv.x;
            myv[nc] = __int_as_float(kv.y);
            vmax = fmaxf(vmax, myv[nc]);
            ++nc;
        }
#pragma unroll
        for (int msk = 1; msk < 64; msk <<= 1)
            vmax = fmaxf(vmax, __shfl_xor(vmax, msk));
        float fthr = vmax - MARGIN;
        for (int jj = 0; jj < nc; ++jj) {
            if (myv[jj] >= fthr) {
                int k = myk[jj];
                const float* cr = cb + (size_t)k * 256;
                float d = 0.f;
                for (int c = 0; c < 256; c += 4) {
                    floatx4 wv = *(const floatx4*)(cr + c);
                    d = fmaf(z[c], wv[0], d);
                    d = fmaf(z[c + 1], wv[1], d);
                    d = fmaf(z[c + 2], wv[2], d);
                    d = fmaf(z[c + 3], wv[3], d);
                }
                float u = zn - 2.0f * d;
                if (u < bu || (u == bu && k < bk)) { bu = u; bk = k; }
            }
        }
    } else {
        // fallback: exact scan of all K with 4 independent chains (cold path)
        for (int kb = l; kb < K_ENT; kb += 256) {
            const float* p0 = cb + (size_t)(kb)       * 256;
            const float* p1 = cb + (size_t)(kb + 64)  * 256;
            const float* p2 = cb + (size_t)(kb + 128) * 256;
            const float* p3 = cb + (size_t)(kb + 192) * 256;
            float d0 = 0.f, d1 = 0.f, d2 = 0.f, d3 = 0.f;
            for (int c = 0; c < 256; c += 4) {
                floatx4 w0 = *(const floatx4*)(p0 + c);
                floatx4 w1 = *(const floatx4*)(p1 + c);
                floatx4 w2 = *(const floatx4*)(p2 + c);
                floatx4 w3 = *(const floatx4*)(p3 + c);
#pragma unroll
                for (int j = 0; j < 4; ++j) {
                    d0 = fmaf(z[c + j], w0[j], d0);
                    d1 = fmaf(z[c + j], w1[j], d1);
                    d2 = fmaf(z[c + j], w2[j], d2);
                    d3 = fmaf(z[c + j], w3[j], d3);
                }
            }
            float u0 = zn - 2.0f * d0, u1 = zn - 2.0f * d1;
            float u2 = zn - 2.0f * d2, u3 = zn - 2.0f * d3;
            // ascending k order preserves first-index tie-break
            if (u0 < bu) { bu = u0; bk = kb; }
            if (u1 < bu) { bu = u1; bk = kb + 64; }
            if (u2 < bu) { bu = u2; bk = kb + 128; }
            if (u3 < bu) { bu = u3; bk = kb + 192; }
        }
    }
#pragma unroll
    for (int msk = 1; msk < 64; msk <<= 1) {
        float ou = __shfl_xor(bu, msk);
        int   ok2 = __shfl_xor(bk, msk);
        if (ou < bu || (ou == bu && ok2 < bk)) { bu = ou; bk = ok2; }
    }
    if (l == 0) { idxi[n] = bk; idxf[n] = (float)bk; }
}

// Gather z_q + loss (coalesced codebook reads via LDS transpose), with fused
// last-block loss finalization (device-scope atomics + threadfence).
__global__ __launch_bounds__(256) void k_gather(const float* __restrict__ zin,
                                                const float* __restrict__ cb,
                                                const int* __restrict__ idxi,
                                                float* __restrict__ out,
                                                double* __restrict__ acc,
                                                int* __restrict__ cnt2) {
    __shared__ float tile[64][65];
    __shared__ int lk[64];
    __shared__ float wsum[4];
    int t = threadIdx.x;
    int blk = blockIdx.x;
    int b = blk >> 6;
    int s0 = (blk & 63) << 6;
    int n0 = (b << 12) + s0;
    if (t < 64) lk[t] = idxi[n0 + t];
    __syncthreads();
    int wv = t >> 6, ln = t & 63;
    float ls = 0.f;
#pragma unroll
    for (int ct = 0; ct < 4; ++ct) {
        int c0 = ct << 6;
#pragma unroll
        for (int i = 0; i < 16; ++i) {
            int sl = (wv << 4) + i;
            tile[sl][ln] = cb[(size_t)lk[sl] * 256 + c0 + ln];   // 256 B coalesced
        }
        __syncthreads();
        const float* zb = zin + ((size_t)b << 20);
        float* ob = out + ((size_t)b << 20);
#pragma unroll
        for (int j = 0; j < 16; ++j) {
            int cl = (wv << 4) + j;
            size_t o = (size_t)(c0 + cl) * 4096 + s0 + ln;
            float v = tile[ln][cl];       // stride-65: 2-way bank alias (free)
            float zv = zb[o];
            ob[o] = v;
            float d = v - zv;
            ls = fmaf(d, d, ls);
        }
        __syncthreads();
    }
#pragma unroll
    for (int msk = 1; msk < 64; msk <<= 1) ls += __shfl_xor(ls, msk);
    if (ln == 0) wsum[wv] = ls;
    __syncthreads();
    if (t == 0) {
        float tot = (wsum[0] + wsum[1]) + (wsum[2] + wsum[3]);
        atomicAdd(acc, (double)tot);
        __threadfence();
        int done = atomicAdd(cnt2, 1);
        if (done == (int)gridDim.x - 1) {
            __threadfence();
            double v = atomicAdd(acc, 0.0);   // coherent read after all adds
            out[LOSS_OFF] = (float)(2.0 * v / 8388608.0);
        }
    }
}

extern "C" void kernel_launch(void* const* d_in, const int* in_sizes, int n_in,
                              void* d_out, int out_size, void* d_ws, size_t ws_size,
                              hipStream_t stream) {
    (void)in_sizes; (void)n_in; (void)out_size;
    const float* z  = (const float*)d_in[0];
    const float* cb = (const float*)d_in[1];
    float* out = (float*)d_out;
    char* ws = (char*)d_ws;

    size_t off = 0;
    ushort_t* zsw  = (ushort_t*)(ws + off); off += 16777216;   // bf16 swizzled z
    ushort_t* cbsw = (ushort_t*)(ws + off); off += 4194304;    // bf16 swizzled codebook
    float* ztf = nullptr;
    const size_t ZTF_BYTES = 33554432;                          // fp32 transposed z
    const size_t SURV_BYTES = (size_t)N_ROWS * 4 * CAP_Q * 8;   // int2 lists (46 MB)
    const size_t TAIL = SURV_BYTES + 524288 + 131072 + 64;
    if (ws_size >= off + ZTF_BYTES + TAIL) { ztf = (float*)(ws + off); off += ZTF_BYTES; }
    int2* surv = (int2*)(ws + off); off += SURV_BYTES;
    int* cnt  = (int*)(ws + off); off += 524288;               // [n][quarter]
    int* idxi = (int*)(ws + off); off += 131072;
    double* acc = (double*)(ws + off); off += 8;
    int* cnt2 = (int*)(ws + off);

    k_prep<<<3072, 256, 0, stream>>>(z, cb, zsw, cbsw, ztf, cnt, cnt2, acc);
    k_screen<<<512, 256, 0, stream>>>(zsw, cbsw, surv, cnt);
    k_refine<<<8192, 256, 0, stream>>>(z, ztf, cb, surv, cnt, idxi, out + IDX_OFF);
    k_gather<<<8192 / 16, 256, 0, stream>>>(z, cb, idxi, out, acc, cnt2);
}

// Round 3
// 382.025 us; speedup vs baseline: 1.3490x; 1.3490x over previous
//
#include <hip/hip_runtime.h>
#include <hip/hip_bf16.h>
#include <stdint.h>
#include <stddef.h>

typedef unsigned short ushort_t;
typedef unsigned int uint_t;

typedef __attribute__((ext_vector_type(8))) short short8;
typedef __attribute__((ext_vector_type(4))) float floatx4;
typedef __attribute__((ext_vector_type(16))) float floatx16;
typedef __attribute__((ext_vector_type(4))) uint_t uintx4;

#define N_ROWS 32768
#define K_ENT  8192
#define CDIM   256
#define OUT_ELEMS 8388608
#define LOSS_OFF  8388608
#define IDX_OFF   8388609
// Per-(row, k-quarter) survivor list capacity. Measured (r8): single-pass
// running-max appends are ~20 per quarter; CAP_Q=44 puts overflow at ~1e-6.
#define CAP_Q  44
// Margin: covers bf16 rounding of z,c + reference fp32 quantization ulp(256).
// Refine re-filters stored candidates against the FINAL row max (max of stored
// vals), reproducing the two-phase survivor set. MFMA accumulation-order
// perturbation (~1e-10) negligible vs MARGIN.
#define MARGIN    2.0e-4f

// RNE float -> bf16 bits
__device__ __forceinline__ ushort_t f2bf(float f) {
    uint_t x = __float_as_uint(f);
    uint_t r = (x + 0x7fffu + ((x >> 16) & 1u)) >> 16;
    return (ushort_t)r;
}

// Swizzled layout for mfma_32x32x16 fragments: element (row, c) lives at
//   (row>>5)*8192 + (c>>4)*512 + ((c>>3)&1)*256 + (row&31)*8 + (c&7)   [ushort idx]
// -> fragment load for k-step s (lane l: row r0+(l&31), dims s*16+(l>>5)*8, 16 B)
//    is one contiguous 1 KiB per (rowgroup, s); a 32-ent tile is 16 KB contiguous
//    and LINEAR -> global_load_lds(16B) staging works with a linear LDS dest.

__device__ __forceinline__ void gload_lds16(const ushort_t* g, ushort_t* s) {
    __builtin_amdgcn_global_load_lds(
        (__attribute__((address_space(1))) void*)(g),
        (__attribute__((address_space(3))) void*)(s), 16, 0, 0);
}

// Fused prep: blocks [0,2048) transpose z -> swizzled bf16 (+ fp32 ztf copy);
// blocks [2048,3072) pack codebook -> swizzled bf16 and init cnt/cnt2/acc.
__global__ __launch_bounds__(256) void k_prep(const float* __restrict__ zin,
                                              const float* __restrict__ cb,
                                              ushort_t* __restrict__ zsw,
                                              ushort_t* __restrict__ cbsw,
                                              float* __restrict__ ztf,
                                              int* __restrict__ cnt,
                                              int* __restrict__ cnt2,
                                              double* __restrict__ acc) {
    int bid = blockIdx.x;
    if (bid >= 2048) {
        int t = (bid - 2048) * 256 + threadIdx.x;   // 262,144 items
        if (t < N_ROWS * 4) cnt[t] = 0;
        if (t == 0) { *acc = 0.0; *cnt2 = 0; }
        int ent = t >> 5;
        int c0  = (t & 31) << 3;
        const float* p = cb + (size_t)ent * CDIM + c0;
        floatx4 f0 = *(const floatx4*)p;
        floatx4 f1 = *(const floatx4*)(p + 4);
        uintx4 pk;
        pk[0] = (uint_t)f2bf(f0[0]) | ((uint_t)f2bf(f0[1]) << 16);
        pk[1] = (uint_t)f2bf(f0[2]) | ((uint_t)f2bf(f0[3]) << 16);
        pk[2] = (uint_t)f2bf(f1[0]) | ((uint_t)f2bf(f1[1]) << 16);
        pk[3] = (uint_t)f2bf(f1[2]) | ((uint_t)f2bf(f1[3]) << 16);
        int idx = (ent >> 5) * 8192 + (c0 >> 4) * 512 + ((c0 >> 3) & 1) * 256 + (ent & 31) * 8;
        *(uintx4*)(cbsw + idx) = pk;
        return;
    }
    __shared__ float lds[64][65];
    int c0 = (bid & 3) << 6;
    int s0 = ((bid >> 2) & 63) << 6;
    int b  = bid >> 8;
    int tid = threadIdx.x;
    int j = tid & 63, ib = tid >> 6;
    const float* zb = zin + ((size_t)b << 20);
#pragma unroll
    for (int rr = 0; rr < 16; ++rr) {
        int i = rr * 4 + ib;                       // c-local
        lds[i][j] = zb[(size_t)(c0 + i) * 4096 + s0 + j];   // coalesced over j
    }
    __syncthreads();
#pragma unroll
    for (int it = 0; it < 2; ++it) {
        int item = it * 256 + tid;                 // 512 items: (s-local, c-chunk)
        int sl = item >> 3;
        int ch = item & 7;
        int row = (b << 12) + s0 + sl;             // n
        int cg  = c0 + ch * 8;
        uintx4 pk;
        floatx4 f0, f1;
#pragma unroll
        for (int q = 0; q < 4; ++q) {
            float a = lds[ch * 8 + 2 * q][sl];
            float bqv = lds[ch * 8 + 2 * q + 1][sl];
            pk[q] = (uint_t)f2bf(a) | ((uint_t)f2bf(bqv) << 16);
        }
#pragma unroll
        for (int q = 0; q < 4; ++q) {
            f0[q] = lds[ch * 8 + q][sl];
            f1[q] = lds[ch * 8 + 4 + q][sl];
        }
        int idx = (row >> 5) * 8192 + (cg >> 4) * 512 + ((cg >> 3) & 1) * 256 + (row & 31) * 8;
        *(uintx4*)(zsw + idx) = pk;
        if (ztf) {
            *(floatx4*)(ztf + (size_t)row * 256 + cg) = f0;
            *(floatx4*)(ztf + (size_t)row * 256 + cg + 4) = f1;
        }
    }
}

// Per-tile max-reduce + survivor append, BATCHED: build a 16-bit hit mask with
// VALU compares, ONE atomicAdd(popc) per lane (lanes hit different rows ->
// parallel at L2, and only a single in-flight return dependency per wave
// instead of a serial same-address chain), then exec-masked fire-and-forget
// stores. C/D layout (32x32x16): col(z-row)=lane&31, ent=(r&3)+8*(r>>2)+4*(l>>5).
__device__ __forceinline__ void screen_emit(const floatx16& acc, float& rmx,
                                            int2* slist, int* cntp, int ent0) {
    float t0 = fmaxf(fmaxf(acc[0], acc[1]), fmaxf(acc[2], acc[3]));
    float t1 = fmaxf(fmaxf(acc[4], acc[5]), fmaxf(acc[6], acc[7]));
    float t2 = fmaxf(fmaxf(acc[8], acc[9]), fmaxf(acc[10], acc[11]));
    float t3 = fmaxf(fmaxf(acc[12], acc[13]), fmaxf(acc[14], acc[15]));
    float mx = fmaxf(fmaxf(t0, t1), fmaxf(t2, t3));
    mx = fmaxf(mx, __shfl_xor(mx, 32));   // other lane-half holds other 16 ents
    float rm = fmaxf(rmx, mx);
    rmx = rm;
    float thr = rm - MARGIN;
    uint_t mask = 0u;
#pragma unroll
    for (int r = 0; r < 16; ++r)
        if (acc[r] >= thr) mask |= (1u << r);
    if (mask) {
        int s = atomicAdd(cntp, __popc(mask));
#pragma unroll
        for (int r = 0; r < 16; ++r) {
            if (mask & (1u << r)) {
                if (s < CAP_Q)
                    slist[s] = make_int2(ent0 + (r & 3) + 8 * (r >> 2),
                                         __float_as_int(acc[r]));
                ++s;
            }
        }
    }
}

// SINGLE-PASS bf16 MFMA screen, 32x32x16, entries on the accumulator register
// axis, z-rows on the lane axis. ROUND 3: round-1 geometry restored (32 rows/
// wave, 1024 blocks, ~13 waves/CU — round-2's 64-row waves halved occupancy
// and regressed) + batched survivor append (the serial per-r atomic chain was
// the exposed per-kt latency: vmcnt(0) at the barrier waited on up to 16
// dependent same-address L2 round-trips). s_setprio(1) wraps the MFMA cluster
// (blocks are phase-staggered — T5's favorable regime).
// Append semantics unchanged: any value within MARGIN of the RUNNING row max
// is stored; refine re-filters against the final max (= max stored value;
// record-setter always self-appends), reproducing the two-phase survivor set.
__global__ __launch_bounds__(256, 4) void k_screen(const ushort_t* __restrict__ zsw,
                                                   const ushort_t* __restrict__ cbsw,
                                                   int2* __restrict__ surv,
                                                   int* __restrict__ cnt) {
    __shared__ ushort_t bt[2][8192];    // 2 x 16 KB B tiles (32 ents each, linear)
    int tid = threadIdx.x;              // 0..255
    int w = tid >> 6, l = tid & 63;
    int bid = blockIdx.x;
    int q  = bid & 3;                   // k-quarter
    int RB = (bid >> 2) * 128;          // row base; wave w owns rows [RB+w*32, +32)
    int n = RB + w * 32 + (l & 31);     // this lane's z-row
    int cidx = n * 4 + q;
    int2* slist = surv + (size_t)cidx * CAP_Q;
    int tile0 = q * 64;                 // first 32-ent tile of this quarter

    // prologue: stage tile 0 into buf 0 (16 KB = 256 threads x 16 B x 4)
#pragma unroll
    for (int j = 0; j < 4; ++j)
        gload_lds16(cbsw + (size_t)tile0 * 8192 + j * 2048 + tid * 8,
                    &bt[0][j * 2048 + w * 512]);

    // z fragments (B operand: rows on lanes, 16 k-steps) held in regs all kernel
    short8 zfr[16];
    {
        const ushort_t* pz = zsw + (size_t)((RB >> 5) + w) * 8192 + l * 8;
#pragma unroll
        for (int s = 0; s < 16; ++s)
            zfr[s] = *(const short8*)(pz + s * 512);
    }
    __syncthreads();

    float rmx = -3.0e38f;               // running row max (same in both halves)
    int esub = (l >> 5) * 4;            // C/D ent = (r&3) + 8*(r>>2) + 4*(l>>5)

    for (int kt = 0; kt < 64; ++kt) {
        // prefetch next tile into other buffer (last iter re-stages tile 0)
        int bsel = (kt + 1) & 1;
        const ushort_t* gs = cbsw + (size_t)(tile0 + ((kt + 1) & 63)) * 8192;
#pragma unroll
        for (int j = 0; j < 4; ++j)
            gload_lds16(gs + j * 2048 + tid * 8, &bt[bsel][j * 2048 + w * 512]);

        const ushort_t* bb = &bt[kt & 1][l * 8];
        floatx16 acc;
#pragma unroll
        for (int i = 0; i < 16; ++i) acc[i] = 0.f;
        __builtin_amdgcn_s_setprio(1);
#pragma unroll
        for (int s = 0; s < 16; ++s) {
            short8 a = *(const short8*)(bb + s * 512);   // codebook frag (A: ents)
            acc = __builtin_amdgcn_mfma_f32_32x32x16_bf16(a, zfr[s], acc, 0, 0, 0);
        }
        __builtin_amdgcn_s_setprio(0);
        int ent0 = (tile0 + kt) * 32 + esub;
        screen_emit(acc, rmx, slist, &cnt[cidx], ent0);
        __syncthreads();                // drains vmcnt: next tile ready, buf reusable
    }
}

// Exact fp32 refine: gather <=176 stored (ent, bf16-dot) candidates from the 4
// quarter lists, filter by val >= finalmax - MARGIN (finalmax = max stored val;
// the record-setter always self-appends), then fp32 dots for the ~1-3 passing
// candidates. Serial fmaf order unchanged, so idx semantics are unchanged.
// Overflow (~1e-6 probability) -> 4-chain fast full-scan fallback.
__global__ __launch_bounds__(256) void k_refine(const float* __restrict__ zin,
                                                const float* __restrict__ ztf,
                                                const float* __restrict__ cb,
                                                const int2* __restrict__ surv,
                                                const int* __restrict__ cnt,
                                                int* __restrict__ idxi,
                                                float* __restrict__ idxf) {
    __shared__ float zr[4][256];
    int w = threadIdx.x >> 6, l = threadIdx.x & 63;
    int n = blockIdx.x * 4 + w;
    if (ztf) {
        const float* zrow = ztf + (size_t)n * 256;
#pragma unroll
        for (int i = 0; i < 4; ++i)
            zr[w][l + 64 * i] = zrow[l + 64 * i];          // coalesced
    } else {
        int b = n >> 12, s = n & 4095;
        const float* zb = zin + ((size_t)b << 20) + s;
#pragma unroll
        for (int i = 0; i < 4; ++i)
            zr[w][l + 64 * i] = zb[(size_t)(l + 64 * i) << 12];
    }
    __syncthreads();
    const float* z = zr[w];
    float zn = 0.f;
    for (int c = 0; c < 256; ++c) zn = fmaf(z[c], z[c], zn);

    int c0 = cnt[n * 4 + 0], c1 = cnt[n * 4 + 1];
    int c2 = cnt[n * 4 + 2], c3 = cnt[n * 4 + 3];
    int m = c0 + c1 + c2 + c3;
    bool ok = (c0 <= CAP_Q) && (c1 <= CAP_Q) && (c2 <= CAP_Q) && (c3 <= CAP_Q) && (m >= 1);
    float bu = 3.0e38f;
    int bk = 0x7fffffff;
    if (ok) {
        int myk[3]; float myv[3]; int nc = 0;
        float vmax = -3.0e38f;
        for (int i = l; i < m; i += 64) {
            int qq, s;
            if (i < c0)            { qq = 0; s = i; }
            else if (i < c0 + c1)  { qq = 1; s = i - c0; }
            else if (i < c0 + c1 + c2) { qq = 2; s = i - c0 - c1; }
            else                   { qq = 3; s = i - c0 - c1 - c2; }
            int2 kv = surv[(n * 4 + qq) * CAP_Q + s];
            myk[nc] = kv.x;
            myv[nc] = __int_as_float(kv.y);
            vmax = fmaxf(vmax, myv[nc]);
            ++nc;
        }
#pragma unroll
        for (int msk = 1; msk < 64; msk <<= 1)
            vmax = fmaxf(vmax, __shfl_xor(vmax, msk));
        float fthr = vmax - MARGIN;
        for (int jj = 0; jj < nc; ++jj) {
            if (myv[jj] >= fthr) {
                int k = myk[jj];
                const float* cr = cb + (size_t)k * 256;
                float d = 0.f;
                for (int c = 0; c < 256; c += 4) {
                    floatx4 wv = *(const floatx4*)(cr + c);
                    d = fmaf(z[c], wv[0], d);
                    d = fmaf(z[c + 1], wv[1], d);
                    d = fmaf(z[c + 2], wv[2], d);
                    d = fmaf(z[c + 3], wv[3], d);
                }
                float u = zn - 2.0f * d;
                if (u < bu || (u == bu && k < bk)) { bu = u; bk = k; }
            }
        }
    } else {
        // fallback: exact scan of all K with 4 independent chains (cold path)
        for (int kb = l; kb < K_ENT; kb += 256) {
            const float* p0 = cb + (size_t)(kb)       * 256;
            const float* p1 = cb + (size_t)(kb + 64)  * 256;
            const float* p2 = cb + (size_t)(kb + 128) * 256;
            const float* p3 = cb + (size_t)(kb + 192) * 256;
            float d0 = 0.f, d1 = 0.f, d2 = 0.f, d3 = 0.f;
            for (int c = 0; c < 256; c += 4) {
                floatx4 w0 = *(const floatx4*)(p0 + c);
                floatx4 w1 = *(const floatx4*)(p1 + c);
                floatx4 w2 = *(const floatx4*)(p2 + c);
                floatx4 w3 = *(const floatx4*)(p3 + c);
#pragma unroll
                for (int j = 0; j < 4; ++j) {
                    d0 = fmaf(z[c + j], w0[j], d0);
                    d1 = fmaf(z[c + j], w1[j], d1);
                    d2 = fmaf(z[c + j], w2[j], d2);
                    d3 = fmaf(z[c + j], w3[j], d3);
                }
            }
            float u0 = zn - 2.0f * d0, u1 = zn - 2.0f * d1;
            float u2 = zn - 2.0f * d2, u3 = zn - 2.0f * d3;
            // ascending k order preserves first-index tie-break
            if (u0 < bu) { bu = u0; bk = kb; }
            if (u1 < bu) { bu = u1; bk = kb + 64; }
            if (u2 < bu) { bu = u2; bk = kb + 128; }
            if (u3 < bu) { bu = u3; bk = kb + 192; }
        }
    }
#pragma unroll
    for (int msk = 1; msk < 64; msk <<= 1) {
        float ou = __shfl_xor(bu, msk);
        int   ok2 = __shfl_xor(bk, msk);
        if (ou < bu || (ou == bu && ok2 < bk)) { bu = ou; bk = ok2; }
    }
    if (l == 0) { idxi[n] = bk; idxf[n] = (float)bk; }
}

// Gather z_q + loss (coalesced codebook reads via LDS transpose), with fused
// last-block loss finalization (device-scope atomics + threadfence).
__global__ __launch_bounds__(256) void k_gather(const float* __restrict__ zin,
                                                const float* __restrict__ cb,
                                                const int* __restrict__ idxi,
                                                float* __restrict__ out,
                                                double* __restrict__ acc,
                                                int* __restrict__ cnt2) {
    __shared__ float tile[64][65];
    __shared__ int lk[64];
    __shared__ float wsum[4];
    int t = threadIdx.x;
    int blk = blockIdx.x;
    int b = blk >> 6;
    int s0 = (blk & 63) << 6;
    int n0 = (b << 12) + s0;
    if (t < 64) lk[t] = idxi[n0 + t];
    __syncthreads();
    int wv = t >> 6, ln = t & 63;
    float ls = 0.f;
#pragma unroll
    for (int ct = 0; ct < 4; ++ct) {
        int c0 = ct << 6;
#pragma unroll
        for (int i = 0; i < 16; ++i) {
            int sl = (wv << 4) + i;
            tile[sl][ln] = cb[(size_t)lk[sl] * 256 + c0 + ln];   // 256 B coalesced
        }
        __syncthreads();
        const float* zb = zin + ((size_t)b << 20);
        float* ob = out + ((size_t)b << 20);
#pragma unroll
        for (int j = 0; j < 16; ++j) {
            int cl = (wv << 4) + j;
            size_t o = (size_t)(c0 + cl) * 4096 + s0 + ln;
            float v = tile[ln][cl];       // stride-65: 2-way bank alias (free)
            float zv = zb[o];
            ob[o] = v;
            float d = v - zv;
            ls = fmaf(d, d, ls);
        }
        __syncthreads();
    }
#pragma unroll
    for (int msk = 1; msk < 64; msk <<= 1) ls += __shfl_xor(ls, msk);
    if (ln == 0) wsum[wv] = ls;
    __syncthreads();
    if (t == 0) {
        float tot = (wsum[0] + wsum[1]) + (wsum[2] + wsum[3]);
        atomicAdd(acc, (double)tot);
        __threadfence();
        int done = atomicAdd(cnt2, 1);
        if (done == (int)gridDim.x - 1) {
            __threadfence();
            double v = atomicAdd(acc, 0.0);   // coherent read after all adds
            out[LOSS_OFF] = (float)(2.0 * v / 8388608.0);
        }
    }
}

extern "C" void kernel_launch(void* const* d_in, const int* in_sizes, int n_in,
                              void* d_out, int out_size, void* d_ws, size_t ws_size,
                              hipStream_t stream) {
    (void)in_sizes; (void)n_in; (void)out_size;
    const float* z  = (const float*)d_in[0];
    const float* cb = (const float*)d_in[1];
    float* out = (float*)d_out;
    char* ws = (char*)d_ws;

    size_t off = 0;
    ushort_t* zsw  = (ushort_t*)(ws + off); off += 16777216;   // bf16 swizzled z
    ushort_t* cbsw = (ushort_t*)(ws + off); off += 4194304;    // bf16 swizzled codebook
    float* ztf = nullptr;
    const size_t ZTF_BYTES = 33554432;                          // fp32 transposed z
    const size_t SURV_BYTES = (size_t)N_ROWS * 4 * CAP_Q * 8;   // int2 lists (46 MB)
    const size_t TAIL = SURV_BYTES + 524288 + 131072 + 64;
    if (ws_size >= off + ZTF_BYTES + TAIL) { ztf = (float*)(ws + off); off += ZTF_BYTES; }
    int2* surv = (int2*)(ws + off); off += SURV_BYTES;
    int* cnt  = (int*)(ws + off); off += 524288;               // [n][quarter]
    int* idxi = (int*)(ws + off); off += 131072;
    double* acc = (double*)(ws + off); off += 8;
    int* cnt2 = (int*)(ws + off);

    k_prep<<<3072, 256, 0, stream>>>(z, cb, zsw, cbsw, ztf, cnt, cnt2, acc);
    k_screen<<<1024, 256, 0, stream>>>(zsw, cbsw, surv, cnt);
    k_refine<<<8192, 256, 0, stream>>>(z, ztf, cb, surv, cnt, idxi, out + IDX_OFF);
    k_gather<<<8192 / 16, 256, 0, stream>>>(z, cb, idxi, out, acc, cnt2);
}

// Round 4
// 364.314 us; speedup vs baseline: 1.4146x; 1.0486x over previous
//
#include <hip/hip_runtime.h>
#include <hip/hip_bf16.h>
#include <stdint.h>
#include <stddef.h>

typedef unsigned short ushort_t;
typedef unsigned int uint_t;

typedef __attribute__((ext_vector_type(8))) short short8;
typedef __attribute__((ext_vector_type(4))) float floatx4;
typedef __attribute__((ext_vector_type(16))) float floatx16;
typedef __attribute__((ext_vector_type(4))) uint_t uintx4;

#define N_ROWS 32768
#define K_ENT  8192
#define CDIM   256
#define OUT_ELEMS 8388608
#define LOSS_OFF  8388608
#define IDX_OFF   8388609
// Per-(row, k-quarter) survivor list capacity. Measured (r8): single-pass
// running-max appends are ~20 per quarter; CAP_Q=44 puts overflow at ~1e-6.
#define CAP_Q  44
// Margin: covers bf16 rounding of z,c + reference fp32 quantization ulp(256).
// Refine re-filters stored candidates against the FINAL row max (max of stored
// vals), reproducing the two-phase survivor set. MFMA accumulation-order
// perturbation (~1e-10) negligible vs MARGIN.
#define MARGIN    2.0e-4f

// RNE float -> bf16 bits
__device__ __forceinline__ ushort_t f2bf(float f) {
    uint_t x = __float_as_uint(f);
    uint_t r = (x + 0x7fffu + ((x >> 16) & 1u)) >> 16;
    return (ushort_t)r;
}

// Swizzled layout for mfma_32x32x16 fragments: element (row, c) lives at
//   (row>>5)*8192 + (c>>4)*512 + ((c>>3)&1)*256 + (row&31)*8 + (c&7)   [ushort idx]
// -> fragment load for k-step s (lane l: row r0+(l&31), dims s*16+(l>>5)*8, 16 B)
//    is one contiguous 1 KiB per (rowgroup, s); a 32-ent tile is 16 KB contiguous
//    and LINEAR -> global_load_lds(16B) staging works with a linear LDS dest.

__device__ __forceinline__ void gload_lds16(const ushort_t* g, ushort_t* s) {
    __builtin_amdgcn_global_load_lds(
        (__attribute__((address_space(1))) void*)(g),
        (__attribute__((address_space(3))) void*)(s), 16, 0, 0);
}

// Fused prep: blocks [0,2048) transpose z -> swizzled bf16 (+ fp32 ztf copy);
// blocks [2048,3072) pack codebook -> swizzled bf16 and init cnt/cnt2/acc.
__global__ __launch_bounds__(256) void k_prep(const float* __restrict__ zin,
                                              const float* __restrict__ cb,
                                              ushort_t* __restrict__ zsw,
                                              ushort_t* __restrict__ cbsw,
                                              float* __restrict__ ztf,
                                              int* __restrict__ cnt,
                                              int* __restrict__ cnt2,
                                              double* __restrict__ acc) {
    int bid = blockIdx.x;
    if (bid >= 2048) {
        int t = (bid - 2048) * 256 + threadIdx.x;   // 262,144 items
        if (t < N_ROWS * 4) cnt[t] = 0;
        if (t == 0) { *acc = 0.0; *cnt2 = 0; }
        int ent = t >> 5;
        int c0  = (t & 31) << 3;
        const float* p = cb + (size_t)ent * CDIM + c0;
        floatx4 f0 = *(const floatx4*)p;
        floatx4 f1 = *(const floatx4*)(p + 4);
        uintx4 pk;
        pk[0] = (uint_t)f2bf(f0[0]) | ((uint_t)f2bf(f0[1]) << 16);
        pk[1] = (uint_t)f2bf(f0[2]) | ((uint_t)f2bf(f0[3]) << 16);
        pk[2] = (uint_t)f2bf(f1[0]) | ((uint_t)f2bf(f1[1]) << 16);
        pk[3] = (uint_t)f2bf(f1[2]) | ((uint_t)f2bf(f1[3]) << 16);
        int idx = (ent >> 5) * 8192 + (c0 >> 4) * 512 + ((c0 >> 3) & 1) * 256 + (ent & 31) * 8;
        *(uintx4*)(cbsw + idx) = pk;
        return;
    }
    __shared__ float lds[64][65];
    int c0 = (bid & 3) << 6;
    int s0 = ((bid >> 2) & 63) << 6;
    int b  = bid >> 8;
    int tid = threadIdx.x;
    int j = tid & 63, ib = tid >> 6;
    const float* zb = zin + ((size_t)b << 20);
#pragma unroll
    for (int rr = 0; rr < 16; ++rr) {
        int i = rr * 4 + ib;                       // c-local
        lds[i][j] = zb[(size_t)(c0 + i) * 4096 + s0 + j];   // coalesced over j
    }
    __syncthreads();
#pragma unroll
    for (int it = 0; it < 2; ++it) {
        int item = it * 256 + tid;                 // 512 items: (s-local, c-chunk)
        int sl = item >> 3;
        int ch = item & 7;
        int row = (b << 12) + s0 + sl;             // n
        int cg  = c0 + ch * 8;
        uintx4 pk;
        floatx4 f0, f1;
#pragma unroll
        for (int q = 0; q < 4; ++q) {
            float a = lds[ch * 8 + 2 * q][sl];
            float bqv = lds[ch * 8 + 2 * q + 1][sl];
            pk[q] = (uint_t)f2bf(a) | ((uint_t)f2bf(bqv) << 16);
        }
#pragma unroll
        for (int q = 0; q < 4; ++q) {
            f0[q] = lds[ch * 8 + q][sl];
            f1[q] = lds[ch * 8 + 4 + q][sl];
        }
        int idx = (row >> 5) * 8192 + (cg >> 4) * 512 + ((cg >> 3) & 1) * 256 + (row & 31) * 8;
        *(uintx4*)(zsw + idx) = pk;
        if (ztf) {
            *(floatx4*)(ztf + (size_t)row * 256 + cg) = f0;
            *(floatx4*)(ztf + (size_t)row * 256 + cg + 4) = f1;
        }
    }
}

// Per-tile max-reduce + survivor append, ATOMIC-FREE: each (row, quarter) list
// is written only by lane l and partner l^32 of ONE wave, so slot allocation is
// in-wave: p=popc(own mask), pp=partner's popc via shfl_xor(32); low lane takes
// [cur, cur+p), high lane [cur+p_low, ...); cur (per-lane VGPR, identical in
// both partners) advances by p+pp. cnt is written ONCE at kernel end. Stores
// are fire-and-forget (no atomic-return dependency on the barrier path).
// C/D layout (32x32x16): col(z-row)=lane&31, ent=(r&3)+8*(r>>2)+4*(l>>5).
__device__ __forceinline__ void screen_emit(const floatx16& acc, float& rmx,
                                            int& cur, int hi, int2* slist,
                                            int ent0) {
    float t0 = fmaxf(fmaxf(acc[0], acc[1]), fmaxf(acc[2], acc[3]));
    float t1 = fmaxf(fmaxf(acc[4], acc[5]), fmaxf(acc[6], acc[7]));
    float t2 = fmaxf(fmaxf(acc[8], acc[9]), fmaxf(acc[10], acc[11]));
    float t3 = fmaxf(fmaxf(acc[12], acc[13]), fmaxf(acc[14], acc[15]));
    float mx = fmaxf(fmaxf(t0, t1), fmaxf(t2, t3));
    mx = fmaxf(mx, __shfl_xor(mx, 32));   // other lane-half holds other 16 ents
    float rm = fmaxf(rmx, mx);
    rmx = rm;
    float thr = rm - MARGIN;
    uint_t mask = 0u;
#pragma unroll
    for (int r = 0; r < 16; ++r)
        if (acc[r] >= thr) mask |= (1u << r);
    int p  = __popc(mask);
    int pp = __shfl_xor(p, 32);           // partner lane's count
    int base = cur + (hi ? pp : 0);       // low-lane slots first (order arbitrary)
    cur += p + pp;                        // symmetric -> stays equal in partners
    if (mask) {
        int s = base;
#pragma unroll
        for (int r = 0; r < 16; ++r) {
            if (mask & (1u << r)) {
                if (s < CAP_Q)
                    slist[s] = make_int2(ent0 + (r & 3) + 8 * (r >> 2),
                                         __float_as_int(acc[r]));
                ++s;
            }
        }
    }
}

// SINGLE-PASS bf16 MFMA screen, 32x32x16, entries on the accumulator register
// axis, z-rows on the lane axis. ROUND 4: atomic-free survivor emit (see
// screen_emit) — removes ~0.64M atomicAdd-with-return round trips whose
// dependent stores drained at every per-kt barrier (the convoy tail). Geometry
// unchanged from round 3 (32 rows/wave, 1024 blocks, 32 KB dbuf LDS).
// Semantics unchanged: any value within MARGIN of the RUNNING row max is
// stored; refine re-filters against the final max (= max stored value;
// record-setter always self-appends), reproducing the two-phase survivor set.
__global__ __launch_bounds__(256, 4) void k_screen(const ushort_t* __restrict__ zsw,
                                                   const ushort_t* __restrict__ cbsw,
                                                   int2* __restrict__ surv,
                                                   int* __restrict__ cnt) {
    __shared__ ushort_t bt[2][8192];    // 2 x 16 KB B tiles (32 ents each, linear)
    int tid = threadIdx.x;              // 0..255
    int w = tid >> 6, l = tid & 63;
    int bid = blockIdx.x;
    int q  = bid & 3;                   // k-quarter
    int RB = (bid >> 2) * 128;          // row base; wave w owns rows [RB+w*32, +32)
    int n = RB + w * 32 + (l & 31);     // this lane's z-row
    int cidx = n * 4 + q;
    int2* slist = surv + (size_t)cidx * CAP_Q;
    int tile0 = q * 64;                 // first 32-ent tile of this quarter
    int hi = l & 32;

    // prologue: stage tile 0 into buf 0 (16 KB = 256 threads x 16 B x 4)
#pragma unroll
    for (int j = 0; j < 4; ++j)
        gload_lds16(cbsw + (size_t)tile0 * 8192 + j * 2048 + tid * 8,
                    &bt[0][j * 2048 + w * 512]);

    // z fragments (B operand: rows on lanes, 16 k-steps) held in regs all kernel
    short8 zfr[16];
    {
        const ushort_t* pz = zsw + (size_t)((RB >> 5) + w) * 8192 + l * 8;
#pragma unroll
        for (int s = 0; s < 16; ++s)
            zfr[s] = *(const short8*)(pz + s * 512);
    }
    __syncthreads();

    float rmx = -3.0e38f;               // running row max (same in both halves)
    int cur = 0;                        // running survivor count for this row
    int esub = (l >> 5) * 4;            // C/D ent = (r&3) + 8*(r>>2) + 4*(l>>5)

    for (int kt = 0; kt < 64; ++kt) {
        // prefetch next tile into other buffer (last iter re-stages tile 0)
        int bsel = (kt + 1) & 1;
        const ushort_t* gs = cbsw + (size_t)(tile0 + ((kt + 1) & 63)) * 8192;
#pragma unroll
        for (int j = 0; j < 4; ++j)
            gload_lds16(gs + j * 2048 + tid * 8, &bt[bsel][j * 2048 + w * 512]);

        const ushort_t* bb = &bt[kt & 1][l * 8];
        floatx16 acc;
#pragma unroll
        for (int i = 0; i < 16; ++i) acc[i] = 0.f;
        __builtin_amdgcn_s_setprio(1);
#pragma unroll
        for (int s = 0; s < 16; ++s) {
            short8 a = *(const short8*)(bb + s * 512);   // codebook frag (A: ents)
            acc = __builtin_amdgcn_mfma_f32_32x32x16_bf16(a, zfr[s], acc, 0, 0, 0);
        }
        __builtin_amdgcn_s_setprio(0);
        int ent0 = (tile0 + kt) * 32 + esub;
        screen_emit(acc, rmx, cur, hi, slist, ent0);
        __syncthreads();                // next tile staged, buf reusable
    }
    if (!hi) cnt[cidx] = cur;           // one writer per (row, quarter)
}

// Exact fp32 refine: gather <=176 stored (ent, bf16-dot) candidates from the 4
// quarter lists, filter by val >= finalmax - MARGIN (finalmax = max stored val;
// the record-setter always self-appends), then fp32 dots for the ~1-3 passing
// candidates. Serial fmaf order unchanged, so idx semantics are unchanged.
// Overflow (~1e-6 probability) -> 4-chain fast full-scan fallback.
__global__ __launch_bounds__(256) void k_refine(const float* __restrict__ zin,
                                                const float* __restrict__ ztf,
                                                const float* __restrict__ cb,
                                                const int2* __restrict__ surv,
                                                const int* __restrict__ cnt,
                                                int* __restrict__ idxi,
                                                float* __restrict__ idxf) {
    __shared__ float zr[4][256];
    int w = threadIdx.x >> 6, l = threadIdx.x & 63;
    int n = blockIdx.x * 4 + w;
    if (ztf) {
        const float* zrow = ztf + (size_t)n * 256;
#pragma unroll
        for (int i = 0; i < 4; ++i)
            zr[w][l + 64 * i] = zrow[l + 64 * i];          // coalesced
    } else {
        int b = n >> 12, s = n & 4095;
        const float* zb = zin + ((size_t)b << 20) + s;
#pragma unroll
        for (int i = 0; i < 4; ++i)
            zr[w][l + 64 * i] = zb[(size_t)(l + 64 * i) << 12];
    }
    __syncthreads();
    const float* z = zr[w];
    float zn = 0.f;
    for (int c = 0; c < 256; ++c) zn = fmaf(z[c], z[c], zn);

    int c0 = cnt[n * 4 + 0], c1 = cnt[n * 4 + 1];
    int c2 = cnt[n * 4 + 2], c3 = cnt[n * 4 + 3];
    int m = c0 + c1 + c2 + c3;
    bool ok = (c0 <= CAP_Q) && (c1 <= CAP_Q) && (c2 <= CAP_Q) && (c3 <= CAP_Q) && (m >= 1);
    float bu = 3.0e38f;
    int bk = 0x7fffffff;
    if (ok) {
        int myk[3]; float myv[3]; int nc = 0;
        float vmax = -3.0e38f;
        for (int i = l; i < m; i += 64) {
            int qq, s;
            if (i < c0)            { qq = 0; s = i; }
            else if (i < c0 + c1)  { qq = 1; s = i - c0; }
            else if (i < c0 + c1 + c2) { qq = 2; s = i - c0 - c1; }
            else                   { qq = 3; s = i - c0 - c1 - c2; }
            int2 kv = surv[(n * 4 + qq) * CAP_Q + s];
            myk[nc] = kv.x;
            myv[nc] = __int_as_float(kv.y);
            vmax = fmaxf(vmax, myv[nc]);
            ++nc;
        }
#pragma unroll
        for (int msk = 1; msk < 64; msk <<= 1)
            vmax = fmaxf(vmax, __shfl_xor(vmax, msk));
        float fthr = vmax - MARGIN;
        for (int jj = 0; jj < nc; ++jj) {
            if (myv[jj] >= fthr) {
                int k = myk[jj];
                const float* cr = cb + (size_t)k * 256;
                float d = 0.f;
                for (int c = 0; c < 256; c += 4) {
                    floatx4 wv = *(const floatx4*)(cr + c);
                    d = fmaf(z[c], wv[0], d);
                    d = fmaf(z[c + 1], wv[1], d);
                    d = fmaf(z[c + 2], wv[2], d);
                    d = fmaf(z[c + 3], wv[3], d);
                }
                float u = zn - 2.0f * d;
                if (u < bu || (u == bu && k < bk)) { bu = u; bk = k; }
            }
        }
    } else {
        // fallback: exact scan of all K with 4 independent chains (cold path)
        for (int kb = l; kb < K_ENT; kb += 256) {
            const float* p0 = cb + (size_t)(kb)       * 256;
            const float* p1 = cb + (size_t)(kb + 64)  * 256;
            const float* p2 = cb + (size_t)(kb + 128) * 256;
            const float* p3 = cb + (size_t)(kb + 192) * 256;
            float d0 = 0.f, d1 = 0.f, d2 = 0.f, d3 = 0.f;
            for (int c = 0; c < 256; c += 4) {
                floatx4 w0 = *(const floatx4*)(p0 + c);
                floatx4 w1 = *(const floatx4*)(p1 + c);
                floatx4 w2 = *(const floatx4*)(p2 + c);
                floatx4 w3 = *(const floatx4*)(p3 + c);
#pragma unroll
                for (int j = 0; j < 4; ++j) {
                    d0 = fmaf(z[c + j], w0[j], d0);
                    d1 = fmaf(z[c + j], w1[j], d1);
                    d2 = fmaf(z[c + j], w2[j], d2);
                    d3 = fmaf(z[c + j], w3[j], d3);
                }
            }
            float u0 = zn - 2.0f * d0, u1 = zn - 2.0f * d1;
            float u2 = zn - 2.0f * d2, u3 = zn - 2.0f * d3;
            // ascending k order preserves first-index tie-break
            if (u0 < bu) { bu = u0; bk = kb; }
            if (u1 < bu) { bu = u1; bk = kb + 64; }
            if (u2 < bu) { bu = u2; bk = kb + 128; }
            if (u3 < bu) { bu = u3; bk = kb + 192; }
        }
    }
#pragma unroll
    for (int msk = 1; msk < 64; msk <<= 1) {
        float ou = __shfl_xor(bu, msk);
        int   ok2 = __shfl_xor(bk, msk);
        if (ou < bu || (ou == bu && ok2 < bk)) { bu = ou; bk = ok2; }
    }
    if (l == 0) { idxi[n] = bk; idxf[n] = (float)bk; }
}

// Gather z_q + loss (coalesced codebook reads via LDS transpose), with fused
// last-block loss finalization (device-scope atomics + threadfence).
__global__ __launch_bounds__(256) void k_gather(const float* __restrict__ zin,
                                                const float* __restrict__ cb,
                                                const int* __restrict__ idxi,
                                                float* __restrict__ out,
                                                double* __restrict__ acc,
                                                int* __restrict__ cnt2) {
    __shared__ float tile[64][65];
    __shared__ int lk[64];
    __shared__ float wsum[4];
    int t = threadIdx.x;
    int blk = blockIdx.x;
    int b = blk >> 6;
    int s0 = (blk & 63) << 6;
    int n0 = (b << 12) + s0;
    if (t < 64) lk[t] = idxi[n0 + t];
    __syncthreads();
    int wv = t >> 6, ln = t & 63;
    float ls = 0.f;
#pragma unroll
    for (int ct = 0; ct < 4; ++ct) {
        int c0 = ct << 6;
#pragma unroll
        for (int i = 0; i < 16; ++i) {
            int sl = (wv << 4) + i;
            tile[sl][ln] = cb[(size_t)lk[sl] * 256 + c0 + ln];   // 256 B coalesced
        }
        __syncthreads();
        const float* zb = zin + ((size_t)b << 20);
        float* ob = out + ((size_t)b << 20);
#pragma unroll
        for (int j = 0; j < 16; ++j) {
            int cl = (wv << 4) + j;
            size_t o = (size_t)(c0 + cl) * 4096 + s0 + ln;
            float v = tile[ln][cl];       // stride-65: 2-way bank alias (free)
            float zv = zb[o];
            ob[o] = v;
            float d = v - zv;
            ls = fmaf(d, d, ls);
        }
        __syncthreads();
    }
#pragma unroll
    for (int msk = 1; msk < 64; msk <<= 1) ls += __shfl_xor(ls, msk);
    if (ln == 0) wsum[wv] = ls;
    __syncthreads();
    if (t == 0) {
        float tot = (wsum[0] + wsum[1]) + (wsum[2] + wsum[3]);
        atomicAdd(acc, (double)tot);
        __threadfence();
        int done = atomicAdd(cnt2, 1);
        if (done == (int)gridDim.x - 1) {
            __threadfence();
            double v = atomicAdd(acc, 0.0);   // coherent read after all adds
            out[LOSS_OFF] = (float)(2.0 * v / 8388608.0);
        }
    }
}

extern "C" void kernel_launch(void* const* d_in, const int* in_sizes, int n_in,
                              void* d_out, int out_size, void* d_ws, size_t ws_size,
                              hipStream_t stream) {
    (void)in_sizes; (void)n_in; (void)out_size;
    const float* z  = (const float*)d_in[0];
    const float* cb = (const float*)d_in[1];
    float* out = (float*)d_out;
    char* ws = (char*)d_ws;

    size_t off = 0;
    ushort_t* zsw  = (ushort_t*)(ws + off); off += 16777216;   // bf16 swizzled z
    ushort_t* cbsw = (ushort_t*)(ws + off); off += 4194304;    // bf16 swizzled codebook
    float* ztf = nullptr;
    const size_t ZTF_BYTES = 33554432;                          // fp32 transposed z
    const size_t SURV_BYTES = (size_t)N_ROWS * 4 * CAP_Q * 8;   // int2 lists (46 MB)
    const size_t TAIL = SURV_BYTES + 524288 + 131072 + 64;
    if (ws_size >= off + ZTF_BYTES + TAIL) { ztf = (float*)(ws + off); off += ZTF_BYTES; }
    int2* surv = (int2*)(ws + off); off += SURV_BYTES;
    int* cnt  = (int*)(ws + off); off += 524288;               // [n][quarter]
    int* idxi = (int*)(ws + off); off += 131072;
    double* acc = (double*)(ws + off); off += 8;
    int* cnt2 = (int*)(ws + off);

    k_prep<<<3072, 256, 0, stream>>>(z, cb, zsw, cbsw, ztf, cnt, cnt2, acc);
    k_screen<<<1024, 256, 0, stream>>>(zsw, cbsw, surv, cnt);
    k_refine<<<8192, 256, 0, stream>>>(z, ztf, cb, surv, cnt, idxi, out + IDX_OFF);
    k_gather<<<8192 / 16, 256, 0, stream>>>(z, cb, idxi, out, acc, cnt2);
}